// Round 11
// baseline (140.528 us; speedup 1.0000x reference)
//
#include <hip/hip_runtime.h>
#include <math.h>

#define BT 32768   // B*T
#define NC 448     // n_embd
#define NH 64      // head_size
#define TT 2048    // T

typedef __bf16 bf16x8 __attribute__((ext_vector_type(8)));
typedef __bf16 bf16x2 __attribute__((ext_vector_type(2)));
typedef float  f32x4  __attribute__((ext_vector_type(4)));

__device__ __forceinline__ unsigned short f2bf(float f) {
  __bf16 h = (__bf16)f;
  return __builtin_bit_cast(unsigned short, h);
}
__device__ __forceinline__ ushort4 f2bf4(float4 v) {
  ushort4 b; b.x = f2bf(v.x); b.y = f2bf(v.y); b.z = f2bf(v.z); b.w = f2bf(v.w);
  return b;
}
__device__ __forceinline__ float bf2f(unsigned short u) {
  return __builtin_bit_cast(float, (unsigned)u << 16);
}

// gfx950 permlane swaps (VALU cross-lane). HW-validated semantics (R8 PV path):
// pl32: a' = [a_r0, a_r1, b_r0, b_r1], b' = [a_r2, a_r3, b_r2, b_r3]  (16-lane rows)
// pl16: a' = [a_r0, b_r0, a_r2, b_r2], b' = [a_r1, b_r1, a_r3, b_r3]
// HAZARD: operands must be provably-distinct values (round-7 NaN: equal SSA
// values got register-coalesced and the swap degenerated). Only used in the PV
// assembly where operands are distinct pku[] values.
__device__ __forceinline__ void pl32s(unsigned &a, unsigned &b) {
  asm("v_permlane32_swap_b32 %0, %1" : "+v"(a), "+v"(b));
}
__device__ __forceinline__ void pl16s(unsigned &a, unsigned &b) {
  asm("v_permlane16_swap_b32 %0, %1" : "+v"(a), "+v"(b));
}

// async global -> LDS copy, 16B per lane (m97 pattern: no VGPR round-trip).
// LDS dest must be wave-uniform base + lane*16 — our tid*16B layouts satisfy it.
__device__ __forceinline__ void gll16(const unsigned short* g, unsigned short* l) {
  __builtin_amdgcn_global_load_lds(
      (const __attribute__((address_space(1))) unsigned int*)g,
      (__attribute__((address_space(3))) unsigned int*)l, 16, 0, 0);
}

// Swizzled 64x64 bf16 tile: element (row, c) at row*64 + (((c>>3) ^ (row&7))<<3) + (c&7)

// ============ W prep: f32 -> bf16, fragment-ordered ============
// Layout: wp[(((p*7 + ch)*8 + g)*64 + r)*8 + e] = bf16( W_p[r][ch*64 + g*8 + e] )
__global__ __launch_bounds__(256) void wprep_kernel(
    const float* __restrict__ Wk, const float* __restrict__ Wq,
    const float* __restrict__ Wv, unsigned short* __restrict__ wp)
{
  int idx = blockIdx.x * 256 + threadIdx.x;   // [0, 3*7*8*64) = [0, 10752)
  int r = idx & 63;
  int t = idx >> 6;
  int g = t & 7; t >>= 3;
  int ch = t % 7, p = t / 7;
  const float* W = (p == 0) ? Wk : ((p == 1) ? Wq : Wv);
  const float* src = &W[(size_t)r * NC + ch * 64 + g * 8];
  float4 a = *(const float4*)src;
  float4 b = *(const float4*)(src + 4);
  *(ushort4*)&wp[(size_t)idx * 8]     = f2bf4(a);
  *(ushort4*)&wp[(size_t)idx * 8 + 4] = f2bf4(b);
}

// ============ fused projection: K, Q, V in one pass over x ============
__global__ __launch_bounds__(256) void proj_kernel(
    const float* __restrict__ x, const unsigned short* __restrict__ wp,
    unsigned short* __restrict__ kws, unsigned short* __restrict__ qws,
    unsigned short* __restrict__ vws)
{
  __shared__ unsigned short xs[2][4096];
  const int tid = threadIdx.x;
  const int w = tid >> 6, lane = tid & 63;
  const int q = lane >> 4, l15 = lane & 15;
  const int r0 = blockIdx.x * 64;

  f32x4 acc[3][4];
#pragma unroll
  for (int p = 0; p < 3; ++p)
#pragma unroll
    for (int t = 0; t < 4; ++t) acc[p][t] = f32x4{0.f, 0.f, 0.f, 0.f};

  const int c0 = (tid & 15) * 4, r_ = tid >> 4;
  const int wbase = (w * 16 + l15) * 8;

  float4 xr[4];
  bf16x8 wfr[3][2], wnx[3][2];
#pragma unroll
  for (int i = 0; i < 4; ++i)
    xr[i] = *(const float4*)&x[(size_t)(r0 + r_ + 16 * i) * NC + c0];
#pragma unroll
  for (int p = 0; p < 3; ++p)
#pragma unroll
    for (int ks = 0; ks < 2; ++ks)
      wfr[p][ks] = *(const bf16x8*)&wp[(size_t)((p * 7 + 0) * 8 + (q + 4 * ks)) * 512 + wbase];

  for (int ch = 0; ch < 7; ++ch) {
    const int cur = ch & 1;
#pragma unroll
    for (int i = 0; i < 4; ++i) {
      int r = r_ + 16 * i;
      int off = r * 64 + (((c0 >> 3) ^ (r & 7)) << 3) + (c0 & 7);
      *(ushort4*)&xs[cur][off] = f2bf4(xr[i]);
    }
    __syncthreads();
    if (ch < 6) {
      int kc = (ch + 1) * 64;
#pragma unroll
      for (int i = 0; i < 4; ++i)
        xr[i] = *(const float4*)&x[(size_t)(r0 + r_ + 16 * i) * NC + kc + c0];
#pragma unroll
      for (int p = 0; p < 3; ++p)
#pragma unroll
        for (int ks = 0; ks < 2; ++ks)
          wnx[p][ks] = *(const bf16x8*)&wp[(size_t)((p * 7 + ch + 1) * 8 + (q + 4 * ks)) * 512 + wbase];
    }
#pragma unroll
    for (int ks = 0; ks < 2; ++ks) {
#pragma unroll
      for (int t = 0; t < 4; ++t) {
        int xrow = t * 16 + l15;
        bf16x8 xf = *(const bf16x8*)&xs[cur][xrow * 64 + (((q + 4 * ks) ^ (xrow & 7)) << 3)];
        acc[0][t] = __builtin_amdgcn_mfma_f32_16x16x32_bf16(wfr[0][ks], xf, acc[0][t], 0, 0, 0);
        acc[1][t] = __builtin_amdgcn_mfma_f32_16x16x32_bf16(xf, wfr[1][ks], acc[1][t], 0, 0, 0);
        acc[2][t] = __builtin_amdgcn_mfma_f32_16x16x32_bf16(xf, wfr[2][ks], acc[2][t], 0, 0, 0);
      }
    }
    if (ch < 6) {
#pragma unroll
      for (int p = 0; p < 3; ++p)
#pragma unroll
        for (int ks = 0; ks < 2; ++ks)
          wfr[p][ks] = wnx[p][ks];
    }
  }

  const size_t tile = (size_t)blockIdx.x * 4096;
#pragma unroll
  for (int t = 0; t < 4; ++t) {
    int j = t * 16 + l15;
    ushort4 bb; bb.x = f2bf(acc[0][t][0]); bb.y = f2bf(acc[0][t][1]);
    bb.z = f2bf(acc[0][t][2]); bb.w = f2bf(acc[0][t][3]);
    *(ushort4*)&kws[tile + j * 64 + (((2 * w + (q >> 1)) ^ (j & 7)) << 3) + ((q & 1) << 2)] = bb;
  }
  {
    const float qs = 0.068161075f;   // log2(e)/sqrt(448)
    int h = w * 16 + l15;
#pragma unroll
    for (int t = 0; t < 4; ++t)
#pragma unroll
      for (int rr = 0; rr < 4; ++rr) {
        int R = r0 + t * 16 + q * 4 + rr;
        qws[(size_t)R * 64 + h] = f2bf(acc[1][t][rr] * qs);
      }
  }
  {
    int h = w * 16 + l15;
#pragma unroll
    for (int t = 0; t < 4; ++t) {
      ushort4 bb; bb.x = f2bf(acc[2][t][0]); bb.y = f2bf(acc[2][t][1]);
      bb.z = f2bf(acc[2][t][2]); bb.w = f2bf(acc[2][t][3]);
      *(ushort4*)&vws[tile + h * 64 + (((2 * t + (q >> 1)) ^ (h & 7)) << 3) + ((q & 1) << 2)] = bb;
    }
  }
}

// ============ flash attention, split-K with 8-tile chunks ============
// R8-verified compute path (shfl_xor reductions, permlane PV assembly).
// NEW: staging via global_load_lds width=16 (m97 pattern) — no VGPR
// round-trip, no ds_write; one barrier per tile:
//   barrier (buf[cur] ready) -> issue async copies for tile it+1 -> compute.
__global__ __launch_bounds__(256) void attn_partial(
    const unsigned short* __restrict__ kws, const unsigned short* __restrict__ qws,
    const unsigned short* __restrict__ vws, float* __restrict__ out,
    unsigned short* __restrict__ opart, float* __restrict__ mlpart)
{
  __shared__ unsigned short ksm[2][4096];
  __shared__ unsigned short vtm[2][4096];
  const int bx = blockIdx.x, b = blockIdx.y;
  int qt = 0, c = 0;
  {
    int idx = bx;
    if (idx < 52) {            // full chunks (nt == 8), longest-qt first
      for (int q2 = 31; q2 >= 7; --q2) {
        int L = (q2 + 1) >> 3;
        if (idx < L) { qt = q2; c = idx; break; }
        idx -= L;
      }
    } else {                   // tail chunks (nt = (qt+1) & 7)
      idx -= 52;
      for (int q2 = 31; q2 >= 0; --q2) {
        if ((q2 + 1) & 7) {
          if (idx == 0) { qt = q2; c = (q2 + 1) >> 3; break; }
          --idx;
        }
      }
    }
  }
  const int kt0 = c * 8;
  const int ktn = min(kt0 + 8, qt + 1);
  const int nt = ktn - kt0;
  const bool direct = (qt <= 7);

  const int tid = threadIdx.x;
  const int w = tid >> 6, lane = tid & 63;
  const int q = lane >> 4, l15 = lane & 15;
  const int t0 = b * TT + qt * 64;

  bf16x8 qf[2];
#pragma unroll
  for (int ks = 0; ks < 2; ++ks)
    qf[ks] = *(const bf16x8*)&qws[(size_t)(t0 + w * 16 + l15) * 64 + 32 * ks + q * 8];

  f32x4 oacc[4];
#pragma unroll
  for (int ht = 0; ht < 4; ++ht) oacc[ht] = f32x4{0.f, 0.f, 0.f, 0.f};
  float m_i = -INFINITY, l_i = 0.f;   // per-lane, row i = w*16 + l15

  // prologue: stage tile 0 into buffer 0 (async)
  {
    const unsigned short* kt_ = kws + (size_t)(b * 32 + kt0) * 4096;
    const unsigned short* vt_ = vws + (size_t)(b * 32 + kt0) * 4096;
    gll16(&kt_[tid * 8],        &ksm[0][tid * 8]);
    gll16(&kt_[2048 + tid * 8], &ksm[0][2048 + tid * 8]);
    gll16(&vt_[tid * 8],        &vtm[0][tid * 8]);
    gll16(&vt_[2048 + tid * 8], &vtm[0][2048 + tid * 8]);
  }

  for (int it = 0; it < nt; ++it) {
    const int kt = kt0 + it;
    const int cur = it & 1;
    __syncthreads();   // buf[cur] ready (compiler drains vmcnt before s_barrier)
    if (it + 1 < nt) {
      const unsigned short* kt_ = kws + (size_t)(b * 32 + kt + 1) * 4096;
      const unsigned short* vt_ = vws + (size_t)(b * 32 + kt + 1) * 4096;
      const int nb = cur ^ 1;
      gll16(&kt_[tid * 8],        &ksm[nb][tid * 8]);
      gll16(&kt_[2048 + tid * 8], &ksm[nb][2048 + tid * 8]);
      gll16(&vt_[tid * 8],        &vtm[nb][tid * 8]);
      gll16(&vt_[2048 + tid * 8], &vtm[nb][2048 + tid * 8]);
    }

    // S^T = K . Q^T : sacc[jt][rr] = S[i = l15][j = 16jt + 4q + rr]
    f32x4 sacc[4];
#pragma unroll
    for (int jt = 0; jt < 4; ++jt) sacc[jt] = f32x4{0.f, 0.f, 0.f, 0.f};
    __builtin_amdgcn_s_setprio(1);
#pragma unroll
    for (int jt = 0; jt < 4; ++jt) {
      int j = jt * 16 + l15;
#pragma unroll
      for (int ks = 0; ks < 2; ++ks) {
        bf16x8 kf = *(const bf16x8*)&ksm[cur][j * 64 + (((q + 4 * ks) ^ (j & 7)) << 3)];
        sacc[jt] = __builtin_amdgcn_mfma_f32_16x16x32_bf16(kf, qf[ks], sacc[jt], 0, 0, 0);
      }
    }
    __builtin_amdgcn_s_setprio(0);

    if (kt == qt) {   // diagonal tile: mask j > i
      int iloc = w * 16 + l15;
#pragma unroll
      for (int jt = 0; jt < 4; ++jt)
#pragma unroll
        for (int rr = 0; rr < 4; ++rr)
          if (jt * 16 + q * 4 + rr > iloc) sacc[jt][rr] = -INFINITY;
    }

    // online softmax with defer-max (THR = 11 in log2 units)
    float mx = -INFINITY;
#pragma unroll
    for (int jt = 0; jt < 4; ++jt)
#pragma unroll
      for (int rr = 0; rr < 4; ++rr) mx = fmaxf(mx, sacc[jt][rr]);
    mx = fmaxf(mx, __shfl_xor(mx, 16));
    mx = fmaxf(mx, __shfl_xor(mx, 32));
    if (!__all(mx <= m_i + 11.0f)) {
      float mn = fmaxf(m_i, mx);
      float alpha = exp2f(m_i - mn);
      m_i = mn;
      l_i *= alpha;
      float a_t[4];
#pragma unroll
      for (int rr = 0; rr < 4; ++rr) a_t[rr] = __shfl(alpha, q * 4 + rr);
#pragma unroll
      for (int ht = 0; ht < 4; ++ht)
#pragma unroll
        for (int rr = 0; rr < 4; ++rr) oacc[ht][rr] *= a_t[rr];
    }
    float rs = 0.f;
#pragma unroll
    for (int jt = 0; jt < 4; ++jt)
#pragma unroll
      for (int rr = 0; rr < 4; ++rr) {
        float pv = exp2f(sacc[jt][rr] - m_i);
        sacc[jt][rr] = pv; rs += pv;
      }
    rs += __shfl_xor(rs, 16);
    rs += __shfl_xor(rs, 32);
    l_i += rs;

    // pack P to bf16 pairs: pku[jt][h2] = {P[i][16jt+4q+2h2], P[i][16jt+4q+2h2+1]}
    unsigned pku[4][2];
#pragma unroll
    for (int jt = 0; jt < 4; ++jt)
#pragma unroll
      for (int h2 = 0; h2 < 2; ++h2) {
        bf16x2 tpk;
        tpk[0] = (__bf16)sacc[jt][2 * h2];
        tpk[1] = (__bf16)sacc[jt][2 * h2 + 1];
        pku[jt][h2] = __builtin_bit_cast(unsigned, tpk);
      }

    // O += P . V — P A-fragments via permlane swaps (R8-verified bit-exact)
    __builtin_amdgcn_s_setprio(1);
#pragma unroll
    for (int ks2 = 0; ks2 < 2; ++ks2) {
      unsigned x0 = pku[2 * ks2][0], z0 = pku[2 * ks2 + 1][0];
      pl32s(x0, z0); pl16s(x0, z0);
      unsigned y0 = pku[2 * ks2][1], w0 = pku[2 * ks2 + 1][1];
      pl32s(y0, w0); pl16s(y0, w0);
      uint4 wds; wds.x = x0; wds.y = y0; wds.z = z0; wds.w = w0;
      bf16x8 pf = __builtin_bit_cast(bf16x8, wds);
#pragma unroll
      for (int ht = 0; ht < 4; ++ht) {
        int h = ht * 16 + l15;
        bf16x8 vf = *(const bf16x8*)&vtm[cur][h * 64 + (((q + 4 * ks2) ^ (h & 7)) << 3)];
        oacc[ht] = __builtin_amdgcn_mfma_f32_16x16x32_bf16(pf, vf, oacc[ht], 0, 0, 0);
      }
    }
    __builtin_amdgcn_s_setprio(0);
  }

  if (direct) {
    float l_t[4];
#pragma unroll
    for (int rr = 0; rr < 4; ++rr) l_t[rr] = __shfl(l_i, q * 4 + rr);
#pragma unroll
    for (int rr = 0; rr < 4; ++rr) {
      float inv = 1.f / l_t[rr];
      int R = t0 + w * 16 + q * 4 + rr;
#pragma unroll
      for (int ht = 0; ht < 4; ++ht)
        out[(size_t)R * 64 + ht * 16 + l15] = oacc[ht][rr] * inv;
    }
  } else {
    const int pre = (qt < 16) ? 2 * (qt - 8) : (qt < 24 ? 16 + 3 * (qt - 16) : 40 + 4 * (qt - 24));
    const size_t slot = (size_t)b * 72 + pre + c;
    unsigned short* Op = opart + slot * 4096;
#pragma unroll
    for (int rr = 0; rr < 4; ++rr) {
      int rloc = w * 16 + q * 4 + rr;
#pragma unroll
      for (int ht = 0; ht < 4; ++ht)
        Op[rloc * 64 + ht * 16 + l15] = f2bf(oacc[ht][rr]);
    }
    if (q == 0) {
      mlpart[slot * 128 + w * 16 + l15]      = m_i;
      mlpart[slot * 128 + 64 + w * 16 + l15] = l_i;
    }
  }
}

// ============ combine: merge 2-4 bf16 partials for qt in [8,32) ============
__global__ __launch_bounds__(256) void combine_kernel(
    const unsigned short* __restrict__ opart, const float* __restrict__ mlpart,
    float* __restrict__ out)
{
  const int qtc = blockIdx.x, b = blockIdx.y;   // qtc 0..23
  const int qt = 8 + qtc;
  const int nc = (qt >> 3) + 1;
  const int pre = (qt < 16) ? 2 * (qt - 8) : (qt < 24 ? 16 + 3 * (qt - 16) : 40 + 4 * (qt - 24));
  const size_t s0 = (size_t)b * 72 + pre;
  const int t = threadIdx.x;
  const int r = t >> 2, c0 = (t & 3) * 16;

  float m = -INFINITY;
  for (int i = 0; i < nc; ++i)
    m = fmaxf(m, mlpart[(s0 + i) * 128 + r]);
  float wsum = 0.f;
  for (int i = 0; i < nc; ++i)
    wsum += exp2f(mlpart[(s0 + i) * 128 + r] - m) * mlpart[(s0 + i) * 128 + 64 + r];
  const float inv = 1.f / wsum;

  float res[16];
#pragma unroll
  for (int u = 0; u < 16; ++u) res[u] = 0.f;
  for (int i = 0; i < nc; ++i) {
    float wi = exp2f(mlpart[(s0 + i) * 128 + r] - m) * inv;
    const unsigned short* O = opart + (s0 + i) * 4096 + r * 64 + c0;
    union { uint4 v; unsigned short e[8]; } u0, u1;
    u0.v = *(const uint4*)&O[0];
    u1.v = *(const uint4*)&O[8];
#pragma unroll
    for (int u = 0; u < 8; ++u) {
      res[u]     += wi * bf2f(u0.e[u]);
      res[8 + u] += wi * bf2f(u1.e[u]);
    }
  }
  float* op = out + (size_t)(b * TT + qt * 64 + r) * 64 + c0;
  *(float4*)&op[0]  = make_float4(res[0], res[1], res[2], res[3]);
  *(float4*)&op[4]  = make_float4(res[4], res[5], res[6], res[7]);
  *(float4*)&op[8]  = make_float4(res[8], res[9], res[10], res[11]);
  *(float4*)&op[12] = make_float4(res[12], res[13], res[14], res[15]);
}

extern "C" void kernel_launch(void* const* d_in, const int* in_sizes, int n_in,
                              void* d_out, int out_size, void* d_ws, size_t ws_size,
                              hipStream_t stream) {
  const float* x  = (const float*)d_in[0];
  const float* Wk = (const float*)d_in[1];
  const float* Wq = (const float*)d_in[2];
  const float* Wv = (const float*)d_in[3];
  unsigned short* kws = (unsigned short*)d_ws;              // 4.19 MB
  unsigned short* qws = kws + (size_t)BT * NH;              // 4.19 MB
  unsigned short* vws = qws + (size_t)BT * NH;              // 4.19 MB
  unsigned short* opart = vws + (size_t)BT * NH;            // 1152 slots * 8 KB = 9.44 MB
  float* mlpart = (float*)(opart + (size_t)1152 * 4096);    // 590 KB  (total ~22.6 MB)
  float* out = (float*)d_out;
  // wprep (172 KB) aliases opart: consumed by proj_kernel before attn writes opart.
  unsigned short* wprep = opart;

  wprep_kernel<<<dim3(42), 256, 0, stream>>>(Wk, Wq, Wv, wprep);
  proj_kernel<<<dim3(512), 256, 0, stream>>>(x, wprep, kws, qws, vws);
  attn_partial<<<dim3(80, 16), 256, 0, stream>>>(kws, qws, vws, out, opart, mlpart);
  combine_kernel<<<dim3(24, 16), 256, 0, stream>>>(opart, mlpart, out);
}

// Round 12
// 136.319 us; speedup vs baseline: 1.0309x; 1.0309x over previous
//
#include <hip/hip_runtime.h>
#include <math.h>

#define BT 32768   // B*T
#define NC 448     // n_embd
#define NH 64      // head_size
#define TT 2048    // T

typedef __bf16 bf16x8 __attribute__((ext_vector_type(8)));
typedef __bf16 bf16x2 __attribute__((ext_vector_type(2)));
typedef float  f32x4  __attribute__((ext_vector_type(4)));

__device__ __forceinline__ unsigned short f2bf(float f) {
  __bf16 h = (__bf16)f;
  return __builtin_bit_cast(unsigned short, h);
}
__device__ __forceinline__ ushort4 f2bf4(float4 v) {
  ushort4 b; b.x = f2bf(v.x); b.y = f2bf(v.y); b.z = f2bf(v.z); b.w = f2bf(v.w);
  return b;
}
__device__ __forceinline__ float bf2f(unsigned short u) {
  return __builtin_bit_cast(float, (unsigned)u << 16);
}

// gfx950 permlane swaps (VALU cross-lane). HW-validated semantics (R8 PV path):
// pl32: a' = [a_r0, a_r1, b_r0, b_r1], b' = [a_r2, a_r3, b_r2, b_r3]  (16-lane rows)
// pl16: a' = [a_r0, b_r0, a_r2, b_r2], b' = [a_r1, b_r1, a_r3, b_r3]
// HAZARD: operands must be provably-distinct values (round-7 NaN: equal SSA
// values got register-coalesced and the swap degenerated). Only used in the PV
// assembly where operands are distinct pku[] values.
__device__ __forceinline__ void pl32s(unsigned &a, unsigned &b) {
  asm("v_permlane32_swap_b32 %0, %1" : "+v"(a), "+v"(b));
}
__device__ __forceinline__ void pl16s(unsigned &a, unsigned &b) {
  asm("v_permlane16_swap_b32 %0, %1" : "+v"(a), "+v"(b));
}

// Swizzled 64x64 bf16 tile: element (row, c) at row*64 + (((c>>3) ^ (row&7))<<3) + (c&7)

// ============ W prep: f32 -> bf16, fragment-ordered ============
// Layout: wp[(((p*7 + ch)*8 + g)*64 + r)*8 + e] = bf16( W_p[r][ch*64 + g*8 + e] )
__global__ __launch_bounds__(256) void wprep_kernel(
    const float* __restrict__ Wk, const float* __restrict__ Wq,
    const float* __restrict__ Wv, unsigned short* __restrict__ wp)
{
  int idx = blockIdx.x * 256 + threadIdx.x;   // [0, 3*7*8*64) = [0, 10752)
  int r = idx & 63;
  int t = idx >> 6;
  int g = t & 7; t >>= 3;
  int ch = t % 7, p = t / 7;
  const float* W = (p == 0) ? Wk : ((p == 1) ? Wq : Wv);
  const float* src = &W[(size_t)r * NC + ch * 64 + g * 8];
  float4 a = *(const float4*)src;
  float4 b = *(const float4*)(src + 4);
  *(ushort4*)&wp[(size_t)idx * 8]     = f2bf4(a);
  *(ushort4*)&wp[(size_t)idx * 8 + 4] = f2bf4(b);
}

// ============ fused projection: K, Q, V in one pass over x ============
__global__ __launch_bounds__(256) void proj_kernel(
    const float* __restrict__ x, const unsigned short* __restrict__ wp,
    unsigned short* __restrict__ kws, unsigned short* __restrict__ qws,
    unsigned short* __restrict__ vws)
{
  __shared__ unsigned short xs[2][4096];
  const int tid = threadIdx.x;
  const int w = tid >> 6, lane = tid & 63;
  const int q = lane >> 4, l15 = lane & 15;
  const int r0 = blockIdx.x * 64;

  f32x4 acc[3][4];
#pragma unroll
  for (int p = 0; p < 3; ++p)
#pragma unroll
    for (int t = 0; t < 4; ++t) acc[p][t] = f32x4{0.f, 0.f, 0.f, 0.f};

  const int c0 = (tid & 15) * 4, r_ = tid >> 4;
  const int wbase = (w * 16 + l15) * 8;

  float4 xr[4];
  bf16x8 wfr[3][2], wnx[3][2];
#pragma unroll
  for (int i = 0; i < 4; ++i)
    xr[i] = *(const float4*)&x[(size_t)(r0 + r_ + 16 * i) * NC + c0];
#pragma unroll
  for (int p = 0; p < 3; ++p)
#pragma unroll
    for (int ks = 0; ks < 2; ++ks)
      wfr[p][ks] = *(const bf16x8*)&wp[(size_t)((p * 7 + 0) * 8 + (q + 4 * ks)) * 512 + wbase];

  for (int ch = 0; ch < 7; ++ch) {
    const int cur = ch & 1;
#pragma unroll
    for (int i = 0; i < 4; ++i) {
      int r = r_ + 16 * i;
      int off = r * 64 + (((c0 >> 3) ^ (r & 7)) << 3) + (c0 & 7);
      *(ushort4*)&xs[cur][off] = f2bf4(xr[i]);
    }
    __syncthreads();
    if (ch < 6) {
      int kc = (ch + 1) * 64;
#pragma unroll
      for (int i = 0; i < 4; ++i)
        xr[i] = *(const float4*)&x[(size_t)(r0 + r_ + 16 * i) * NC + kc + c0];
#pragma unroll
      for (int p = 0; p < 3; ++p)
#pragma unroll
        for (int ks = 0; ks < 2; ++ks)
          wnx[p][ks] = *(const bf16x8*)&wp[(size_t)((p * 7 + ch + 1) * 8 + (q + 4 * ks)) * 512 + wbase];
    }
#pragma unroll
    for (int ks = 0; ks < 2; ++ks) {
#pragma unroll
      for (int t = 0; t < 4; ++t) {
        int xrow = t * 16 + l15;
        bf16x8 xf = *(const bf16x8*)&xs[cur][xrow * 64 + (((q + 4 * ks) ^ (xrow & 7)) << 3)];
        acc[0][t] = __builtin_amdgcn_mfma_f32_16x16x32_bf16(wfr[0][ks], xf, acc[0][t], 0, 0, 0);
        acc[1][t] = __builtin_amdgcn_mfma_f32_16x16x32_bf16(xf, wfr[1][ks], acc[1][t], 0, 0, 0);
        acc[2][t] = __builtin_amdgcn_mfma_f32_16x16x32_bf16(xf, wfr[2][ks], acc[2][t], 0, 0, 0);
      }
    }
    if (ch < 6) {
#pragma unroll
      for (int p = 0; p < 3; ++p)
#pragma unroll
        for (int ks = 0; ks < 2; ++ks)
          wfr[p][ks] = wnx[p][ks];
    }
  }

  const size_t tile = (size_t)blockIdx.x * 4096;
#pragma unroll
  for (int t = 0; t < 4; ++t) {
    int j = t * 16 + l15;
    ushort4 bb; bb.x = f2bf(acc[0][t][0]); bb.y = f2bf(acc[0][t][1]);
    bb.z = f2bf(acc[0][t][2]); bb.w = f2bf(acc[0][t][3]);
    *(ushort4*)&kws[tile + j * 64 + (((2 * w + (q >> 1)) ^ (j & 7)) << 3) + ((q & 1) << 2)] = bb;
  }
  {
    const float qs = 0.068161075f;   // log2(e)/sqrt(448)
    int h = w * 16 + l15;
#pragma unroll
    for (int t = 0; t < 4; ++t)
#pragma unroll
      for (int rr = 0; rr < 4; ++rr) {
        int R = r0 + t * 16 + q * 4 + rr;
        qws[(size_t)R * 64 + h] = f2bf(acc[1][t][rr] * qs);
      }
  }
  {
    int h = w * 16 + l15;
#pragma unroll
    for (int t = 0; t < 4; ++t) {
      ushort4 bb; bb.x = f2bf(acc[2][t][0]); bb.y = f2bf(acc[2][t][1]);
      bb.z = f2bf(acc[2][t][2]); bb.w = f2bf(acc[2][t][3]);
      *(ushort4*)&vws[tile + h * 64 + (((2 * t + (q >> 1)) ^ (h & 7)) << 3) + ((q & 1) << 2)] = bb;
    }
  }
}

// ============ flash attention, split-K with 8-tile chunks ============
// R8-verified structure: uint4 reg staging + ds_write (compiler-overlapped),
// shfl_xor reductions, permlane PV P-fragment assembly.
__global__ __launch_bounds__(256) void attn_partial(
    const unsigned short* __restrict__ kws, const unsigned short* __restrict__ qws,
    const unsigned short* __restrict__ vws, float* __restrict__ out,
    unsigned short* __restrict__ opart, float* __restrict__ mlpart)
{
  __shared__ unsigned short ksm[2][4096];
  __shared__ unsigned short vtm[2][4096];
  const int bx = blockIdx.x, b = blockIdx.y;
  int qt = 0, c = 0;
  {
    int idx = bx;
    if (idx < 52) {            // full chunks (nt == 8), longest-qt first
      for (int q2 = 31; q2 >= 7; --q2) {
        int L = (q2 + 1) >> 3;
        if (idx < L) { qt = q2; c = idx; break; }
        idx -= L;
      }
    } else {                   // tail chunks (nt = (qt+1) & 7)
      idx -= 52;
      for (int q2 = 31; q2 >= 0; --q2) {
        if ((q2 + 1) & 7) {
          if (idx == 0) { qt = q2; c = (q2 + 1) >> 3; break; }
          --idx;
        }
      }
    }
  }
  const int kt0 = c * 8;
  const int ktn = min(kt0 + 8, qt + 1);
  const int nt = ktn - kt0;
  const bool direct = (qt <= 7);

  const int tid = threadIdx.x;
  const int w = tid >> 6, lane = tid & 63;
  const int q = lane >> 4, l15 = lane & 15;
  const int t0 = b * TT + qt * 64;

  bf16x8 qf[2];
#pragma unroll
  for (int ks = 0; ks < 2; ++ks)
    qf[ks] = *(const bf16x8*)&qws[(size_t)(t0 + w * 16 + l15) * 64 + 32 * ks + q * 8];

  f32x4 oacc[4];
#pragma unroll
  for (int ht = 0; ht < 4; ++ht) oacc[ht] = f32x4{0.f, 0.f, 0.f, 0.f};
  float m_i = -INFINITY, l_i = 0.f;   // per-lane, row i = w*16 + l15

  uint4 kr0, kr1, vr0, vr1;
  {
    const unsigned short* kt_ = kws + (size_t)(b * 32 + kt0) * 4096;
    const unsigned short* vt_ = vws + (size_t)(b * 32 + kt0) * 4096;
    kr0 = *(const uint4*)&kt_[tid * 8];  kr1 = *(const uint4*)&kt_[2048 + tid * 8];
    vr0 = *(const uint4*)&vt_[tid * 8];  vr1 = *(const uint4*)&vt_[2048 + tid * 8];
  }

  for (int it = 0; it < nt; ++it) {
    const int kt = kt0 + it;
    const int cur = it & 1;
    *(uint4*)&ksm[cur][tid * 8] = kr0;  *(uint4*)&ksm[cur][2048 + tid * 8] = kr1;
    *(uint4*)&vtm[cur][tid * 8] = vr0;  *(uint4*)&vtm[cur][2048 + tid * 8] = vr1;
    __syncthreads();
    if (it + 1 < nt) {
      const unsigned short* kt_ = kws + (size_t)(b * 32 + kt + 1) * 4096;
      const unsigned short* vt_ = vws + (size_t)(b * 32 + kt + 1) * 4096;
      kr0 = *(const uint4*)&kt_[tid * 8];  kr1 = *(const uint4*)&kt_[2048 + tid * 8];
      vr0 = *(const uint4*)&vt_[tid * 8];  vr1 = *(const uint4*)&vt_[2048 + tid * 8];
    }

    // S^T = K . Q^T : sacc[jt][rr] = S[i = l15][j = 16jt + 4q + rr]
    f32x4 sacc[4];
#pragma unroll
    for (int jt = 0; jt < 4; ++jt) sacc[jt] = f32x4{0.f, 0.f, 0.f, 0.f};
    __builtin_amdgcn_s_setprio(1);
#pragma unroll
    for (int jt = 0; jt < 4; ++jt) {
      int j = jt * 16 + l15;
#pragma unroll
      for (int ks = 0; ks < 2; ++ks) {
        bf16x8 kf = *(const bf16x8*)&ksm[cur][j * 64 + (((q + 4 * ks) ^ (j & 7)) << 3)];
        sacc[jt] = __builtin_amdgcn_mfma_f32_16x16x32_bf16(kf, qf[ks], sacc[jt], 0, 0, 0);
      }
    }
    __builtin_amdgcn_s_setprio(0);

    if (kt == qt) {   // diagonal tile: mask j > i
      int iloc = w * 16 + l15;
#pragma unroll
      for (int jt = 0; jt < 4; ++jt)
#pragma unroll
        for (int rr = 0; rr < 4; ++rr)
          if (jt * 16 + q * 4 + rr > iloc) sacc[jt][rr] = -INFINITY;
    }

    // online softmax with defer-max (THR = 11 in log2 units)
    float mx = -INFINITY;
#pragma unroll
    for (int jt = 0; jt < 4; ++jt)
#pragma unroll
      for (int rr = 0; rr < 4; ++rr) mx = fmaxf(mx, sacc[jt][rr]);
    mx = fmaxf(mx, __shfl_xor(mx, 16));
    mx = fmaxf(mx, __shfl_xor(mx, 32));
    if (!__all(mx <= m_i + 11.0f)) {
      float mn = fmaxf(m_i, mx);
      float alpha = exp2f(m_i - mn);
      m_i = mn;
      l_i *= alpha;
      float a_t[4];
#pragma unroll
      for (int rr = 0; rr < 4; ++rr) a_t[rr] = __shfl(alpha, q * 4 + rr);
#pragma unroll
      for (int ht = 0; ht < 4; ++ht)
#pragma unroll
        for (int rr = 0; rr < 4; ++rr) oacc[ht][rr] *= a_t[rr];
    }
    float rs = 0.f;
#pragma unroll
    for (int jt = 0; jt < 4; ++jt)
#pragma unroll
      for (int rr = 0; rr < 4; ++rr) {
        float pv = exp2f(sacc[jt][rr] - m_i);
        sacc[jt][rr] = pv; rs += pv;
      }
    rs += __shfl_xor(rs, 16);
    rs += __shfl_xor(rs, 32);
    l_i += rs;

    // pack P to bf16 pairs: pku[jt][h2] = {P[i][16jt+4q+2h2], P[i][16jt+4q+2h2+1]}
    unsigned pku[4][2];
#pragma unroll
    for (int jt = 0; jt < 4; ++jt)
#pragma unroll
      for (int h2 = 0; h2 < 2; ++h2) {
        bf16x2 tpk;
        tpk[0] = (__bf16)sacc[jt][2 * h2];
        tpk[1] = (__bf16)sacc[jt][2 * h2 + 1];
        pku[jt][h2] = __builtin_bit_cast(unsigned, tpk);
      }

    // O += P . V — P A-fragments via permlane swaps (R8-verified bit-exact)
    __builtin_amdgcn_s_setprio(1);
#pragma unroll
    for (int ks2 = 0; ks2 < 2; ++ks2) {
      unsigned x0 = pku[2 * ks2][0], z0 = pku[2 * ks2 + 1][0];
      pl32s(x0, z0); pl16s(x0, z0);
      unsigned y0 = pku[2 * ks2][1], w0 = pku[2 * ks2 + 1][1];
      pl32s(y0, w0); pl16s(y0, w0);
      uint4 wds; wds.x = x0; wds.y = y0; wds.z = z0; wds.w = w0;
      bf16x8 pf = __builtin_bit_cast(bf16x8, wds);
#pragma unroll
      for (int ht = 0; ht < 4; ++ht) {
        int h = ht * 16 + l15;
        bf16x8 vf = *(const bf16x8*)&vtm[cur][h * 64 + (((q + 4 * ks2) ^ (h & 7)) << 3)];
        oacc[ht] = __builtin_amdgcn_mfma_f32_16x16x32_bf16(pf, vf, oacc[ht], 0, 0, 0);
      }
    }
    __builtin_amdgcn_s_setprio(0);
  }

  if (direct) {
    float l_t[4];
#pragma unroll
    for (int rr = 0; rr < 4; ++rr) l_t[rr] = __shfl(l_i, q * 4 + rr);
#pragma unroll
    for (int rr = 0; rr < 4; ++rr) {
      float inv = 1.f / l_t[rr];
      int R = t0 + w * 16 + q * 4 + rr;
#pragma unroll
      for (int ht = 0; ht < 4; ++ht)
        out[(size_t)R * 64 + ht * 16 + l15] = oacc[ht][rr] * inv;
    }
  } else {
    const int pre = (qt < 16) ? 2 * (qt - 8) : (qt < 24 ? 16 + 3 * (qt - 16) : 40 + 4 * (qt - 24));
    const size_t slot = (size_t)b * 72 + pre + c;
    unsigned short* Op = opart + slot * 4096;
#pragma unroll
    for (int rr = 0; rr < 4; ++rr) {
      int rloc = w * 16 + q * 4 + rr;
#pragma unroll
      for (int ht = 0; ht < 4; ++ht)
        Op[rloc * 64 + ht * 16 + l15] = f2bf(oacc[ht][rr]);
    }
    if (q == 0) {
      mlpart[slot * 128 + w * 16 + l15]      = m_i;
      mlpart[slot * 128 + 64 + w * 16 + l15] = l_i;
    }
  }
}

// ============ combine: merge 2-4 bf16 partials for qt in [8,32) ============
__global__ __launch_bounds__(256) void combine_kernel(
    const unsigned short* __restrict__ opart, const float* __restrict__ mlpart,
    float* __restrict__ out)
{
  const int qtc = blockIdx.x, b = blockIdx.y;   // qtc 0..23
  const int qt = 8 + qtc;
  const int nc = (qt >> 3) + 1;
  const int pre = (qt < 16) ? 2 * (qt - 8) : (qt < 24 ? 16 + 3 * (qt - 16) : 40 + 4 * (qt - 24));
  const size_t s0 = (size_t)b * 72 + pre;
  const int t = threadIdx.x;
  const int r = t >> 2, c0 = (t & 3) * 16;

  float m = -INFINITY;
  for (int i = 0; i < nc; ++i)
    m = fmaxf(m, mlpart[(s0 + i) * 128 + r]);
  float wsum = 0.f;
  for (int i = 0; i < nc; ++i)
    wsum += exp2f(mlpart[(s0 + i) * 128 + r] - m) * mlpart[(s0 + i) * 128 + 64 + r];
  const float inv = 1.f / wsum;

  float res[16];
#pragma unroll
  for (int u = 0; u < 16; ++u) res[u] = 0.f;
  for (int i = 0; i < nc; ++i) {
    float wi = exp2f(mlpart[(s0 + i) * 128 + r] - m) * inv;
    const unsigned short* O = opart + (s0 + i) * 4096 + r * 64 + c0;
    union { uint4 v; unsigned short e[8]; } u0, u1;
    u0.v = *(const uint4*)&O[0];
    u1.v = *(const uint4*)&O[8];
#pragma unroll
    for (int u = 0; u < 8; ++u) {
      res[u]     += wi * bf2f(u0.e[u]);
      res[8 + u] += wi * bf2f(u1.e[u]);
    }
  }
  float* op = out + (size_t)(b * TT + qt * 64 + r) * 64 + c0;
  *(float4*)&op[0]  = make_float4(res[0], res[1], res[2], res[3]);
  *(float4*)&op[4]  = make_float4(res[4], res[5], res[6], res[7]);
  *(float4*)&op[8]  = make_float4(res[8], res[9], res[10], res[11]);
  *(float4*)&op[12] = make_float4(res[12], res[13], res[14], res[15]);
}

extern "C" void kernel_launch(void* const* d_in, const int* in_sizes, int n_in,
                              void* d_out, int out_size, void* d_ws, size_t ws_size,
                              hipStream_t stream) {
  const float* x  = (const float*)d_in[0];
  const float* Wk = (const float*)d_in[1];
  const float* Wq = (const float*)d_in[2];
  const float* Wv = (const float*)d_in[3];
  unsigned short* kws = (unsigned short*)d_ws;              // 4.19 MB
  unsigned short* qws = kws + (size_t)BT * NH;              // 4.19 MB
  unsigned short* vws = qws + (size_t)BT * NH;              // 4.19 MB
  unsigned short* opart = vws + (size_t)BT * NH;            // 1152 slots * 8 KB = 9.44 MB
  float* mlpart = (float*)(opart + (size_t)1152 * 4096);    // 590 KB  (total ~22.6 MB)
  float* out = (float*)d_out;
  // wprep (172 KB) aliases opart: consumed by proj_kernel before attn writes opart.
  unsigned short* wprep = opart;

  wprep_kernel<<<dim3(42), 256, 0, stream>>>(Wk, Wq, Wv, wprep);
  proj_kernel<<<dim3(512), 256, 0, stream>>>(x, wprep, kws, qws, vws);
  attn_partial<<<dim3(80, 16), 256, 0, stream>>>(kws, qws, vws, out, opart, mlpart);
  combine_kernel<<<dim3(24, 16), 256, 0, stream>>>(opart, mlpart, out);
}